// Round 14
// baseline (179.858 us; speedup 1.0000x reference)
//
#include <hip/hip_runtime.h>
#include <hip/hip_bf16.h>

#define B_ 16
#define S_ 4096
#define C_ 320
#define KK_ 77
#define D_ 768
#define H_ 8
#define DH_ 40
#define KP_ 80           // padded keys per head
#define NP_ (H_ * KP_)   // 640
#define TAU_ 0.1f
#define GAMMA_ 1.0f
#define EPS_ 1e-12f

typedef __bf16 bf16x8 __attribute__((ext_vector_type(8)));
typedef float f32x4 __attribute__((ext_vector_type(4)));
typedef unsigned short ushort8v __attribute__((ext_vector_type(8)));
typedef unsigned int u32;

#define WAITV(N)  asm volatile("s_waitcnt vmcnt(" #N ")" ::: "memory")
#define WAITVL(N) asm volatile("s_waitcnt vmcnt(" #N ") lgkmcnt(0)" ::: "memory")
#define WAITLG()  asm volatile("s_waitcnt lgkmcnt(0)" ::: "memory")
#define BAR()     __builtin_amdgcn_s_barrier()

__device__ __forceinline__ unsigned short f2bf(float f) {
    union { float f; unsigned u; } v; v.f = f;
    unsigned r = v.u + 0x7fffu + ((v.u >> 16) & 1u);
    return (unsigned short)(r >> 16);
}

// async 16B-per-lane global->LDS DMA (lds dest = wave-uniform base + lane*16)
__device__ __forceinline__ void gld16(const unsigned short* g, char* l) {
    __builtin_amdgcn_global_load_lds(
        (const __attribute__((address_space(1))) u32*)g,
        (__attribute__((address_space(3))) u32*)l, 16, 0, 0);
}

// ---------------------------------------------------------------- build_M
__global__ __launch_bounds__(256) void build_M(const float* __restrict__ Wq,
        const float* __restrict__ Wk, const float* __restrict__ Wv,
        const float* __restrict__ Wo, unsigned short* __restrict__ Bmat) {
    const int Dk = blockIdx.x * 256 + threadIdx.x;     // 0..767
    const int h = blockIdx.y;
    const int which = blockIdx.z >> 2;
    const int c0 = (blockIdx.z & 3) * 80;
    __shared__ float wlds[80 * 44];
    for (int i = threadIdx.x; i < 80 * DH_; i += 256) {
        int c = i / DH_, d = i % DH_;
        wlds[c * 44 + d] = which
            ? Wo[(size_t)(h * DH_ + d) * C_ + (c0 + c)]
            : Wq[(size_t)(c0 + c) * C_ + h * DH_ + d];
    }
    float a[DH_];
    const float* Arow = (which ? Wv : Wk) + (size_t)Dk * C_ + h * DH_;
    #pragma unroll
    for (int d = 0; d < DH_; ++d) a[d] = Arow[d];
    __syncthreads();
    const float scale = 0.15811388300841898f;          // 1/sqrt(40)
    for (int c = 0; c < 80; ++c) {
        float s = 0.f;
        #pragma unroll
        for (int q = 0; q < 10; ++q) {
            float4 wv4 = *(const float4*)&wlds[c * 44 + q * 4];
            s += a[q * 4 + 0] * wv4.x + a[q * 4 + 1] * wv4.y
               + a[q * 4 + 2] * wv4.z + a[q * 4 + 3] * wv4.w;
        }
        if (!which) s *= scale;
        int n = which * 2560 + h * C_ + c0 + c;
        Bmat[(size_t)n * D_ + Dk] = f2bf(s);
    }
}

// ---------------------------------------------------------------- prep_ehs
__global__ __launch_bounds__(256) void prep_ehs(const float* __restrict__ ehs,
        const float* __restrict__ harm, unsigned short* __restrict__ ehs_bf,
        float* __restrict__ pen) {
    const int w = threadIdx.x >> 6, l = threadIdx.x & 63;
    const int kk = blockIdx.x * 4 + w, b = blockIdx.y;
    const size_t obase = ((size_t)b * KP_ + kk) * D_;
    if (kk >= KK_) {
        #pragma unroll
        for (int j = 0; j < 12; ++j) ehs_bf[obase + l + j * 64] = 0;
        if (l == 0) pen[b * KP_ + kk] = 0.f;
        return;
    }
    const float* er = ehs + ((size_t)b * KK_ + kk) * D_;
    float ss = 0.f, dd = 0.f, hh = 0.f;
    #pragma unroll
    for (int j = 0; j < 12; ++j) {
        float e = er[l + j * 64], hv = harm[l + j * 64];
        ehs_bf[obase + l + j * 64] = f2bf(e);
        ss += e * e; dd += e * hv; hh += hv * hv;
    }
    #pragma unroll
    for (int off = 32; off; off >>= 1) {
        ss += __shfl_xor(ss, off);
        dd += __shfl_xor(dd, off);
        hh += __shfl_xor(hh, off);
    }
    if (l == 0) {
        float cs = dd / (fmaxf(sqrtf(ss), EPS_) * fmaxf(sqrtf(hh), EPS_));
        pen[b * KP_ + kk] = GAMMA_ * fmaxf(cs - TAU_, 0.f);
    }
}

// ---------------------------------------------------------------- gemm_WpU
__global__ __launch_bounds__(1024) void gemm_WpU(
        const unsigned short* __restrict__ ehs_bf,
        const unsigned short* __restrict__ Bmat,
        unsigned short* __restrict__ Wp, unsigned short* __restrict__ U) {
    const int id = blockIdx.x;               // 160 = 16 b * 10 nt
    const int b = id & 15, nt = id >> 4;
    const int tid = threadIdx.x, w = tid >> 6, l = tid & 63;
    const int lrow = l & 15, lgrp = l >> 4, lk = lgrp * 8;
    __shared__ unsigned short Al[80 * 768];  // 122880 B, swizzled
    char* lds = (char*)Al;

    const unsigned short* Ag = ehs_bf + (size_t)b * KP_ * D_;
    #pragma unroll
    for (int it = 0; it < 8; ++it) {
        int ch = tid + it * 1024;
        if (ch < 7680) {
            int byte = ch * 16, row = byte / 1536;
            int a = byte ^ ((row & 7) << 4);
            *(ushort8v*)(lds + a) = *(const ushort8v*)(Ag + ch * 8);
        }
    }
    const int n0 = nt * 512 + w * 32;
    const unsigned short* Br = Bmat + (size_t)(n0 + lrow) * D_ + lk;
    bf16x8 bC[2], bN[2];
    #pragma unroll
    for (int nf = 0; nf < 2; ++nf)
        bC[nf] = *(const bf16x8*)(Br + (size_t)nf * 16 * D_);
    __syncthreads();

    f32x4 acc[5][2];
    #pragma unroll
    for (int mf = 0; mf < 5; ++mf)
        #pragma unroll
        for (int nf = 0; nf < 2; ++nf) acc[mf][nf] = (f32x4){0.f, 0.f, 0.f, 0.f};
    #pragma unroll
    for (int ks = 0; ks < D_ / 32; ++ks) {
        if (ks < D_ / 32 - 1) {
            #pragma unroll
            for (int nf = 0; nf < 2; ++nf)
                bN[nf] = *(const bf16x8*)(Br + (size_t)nf * 16 * D_ + (ks + 1) * 32);
        }
        bf16x8 af[5];
        #pragma unroll
        for (int mf = 0; mf < 5; ++mf) {
            int row = mf * 16 + lrow;
            int a = (row * 1536 + (ks * 32 + lk) * 2) ^ ((row & 7) << 4);
            af[mf] = *(const bf16x8*)(lds + a);
        }
        __builtin_amdgcn_s_setprio(1);
        #pragma unroll
        for (int mf = 0; mf < 5; ++mf)
            #pragma unroll
            for (int nf = 0; nf < 2; ++nf)
                acc[mf][nf] = __builtin_amdgcn_mfma_f32_16x16x32_bf16(
                    af[mf], bC[nf], acc[mf][nf], 0, 0, 0);
        __builtin_amdgcn_s_setprio(0);
        #pragma unroll
        for (int nf = 0; nf < 2; ++nf) bC[nf] = bN[nf];
    }
    #pragma unroll
    for (int nf = 0; nf < 2; ++nf) {
        const int col = n0 + nf * 16 + lrow;
        if (col < 2560) {
            const int h = col / C_, c = col % C_;
            #pragma unroll
            for (int mf = 0; mf < 5; ++mf)
                #pragma unroll
                for (int r = 0; r < 4; ++r) {
                    int kk = mf * 16 + lgrp * 4 + r;
                    Wp[((size_t)b * NP_ + h * KP_ + kk) * C_ + c] = f2bf(acc[mf][nf][r]);
                }
        } else {
            const int n2 = col - 2560;
            const int h = n2 / C_, c = n2 % C_;
            #pragma unroll
            for (int mf = 0; mf < 5; ++mf)
                #pragma unroll
                for (int r = 0; r < 4; ++r) {
                    int kk = mf * 16 + lgrp * 4 + r;
                    U[((size_t)b * C_ + c) * NP_ + h * KP_ + kk] = f2bf(acc[mf][nf][r]);
                }
        }
    }
}

// ---------------------------------------------------------------- fused attn
// R13: 512 blocks x 512 threads (8 waves), 128 S-rows = 2 x 64-row subtiles.
// Every staged Wp/U byte feeds BOTH subtiles (2x amortization vs R12).
// Phase 1: HS [128][640B] 80KB + WB [640][128B] 80KB (R12 layout), K=64
//          slices, stage-after-read. Wave = head; acc_A + acc_B.
// Phase 2: PB [128][640B] holds P[:, head-half]; two passes over n-halves,
//          U staged once total (R12 slice layout, 2-buf counted). Heads 0-3
//          write P before pass 0; heads 4-7 hold packed P and write before
//          pass 1. acc2 carries across passes.
__global__ __launch_bounds__(512, 2) void fused_attn(
        const float* __restrict__ hs, const unsigned short* __restrict__ Wp,
        const unsigned short* __restrict__ U, const float* __restrict__ pen,
        const float* __restrict__ bo, float* __restrict__ out) {
    const int id = blockIdx.x;                  // 512 = 8 xcd * 64
    const int xcd = id & 7, rest = id >> 3;     // rest 0..63
    const int b = xcd * 2 + (rest >> 5);        // 2 batches per XCD
    const int s0 = (rest & 31) * 128;
    __shared__ __align__(16) char smem[163840];
    char* HS = smem;                            // [0,81920)  hs [128][640B] swz
    char* WB = smem + 81920;                    // [81920,163840) Wp K=64 slice
    char* PB = smem;                            // [0,81920)  P-half (phase 2)
    char* U0 = smem + 81920;                    // U slice bufs 2x40KB
    char* U1 = smem + 122880;
    const int tid = threadIdx.x, w = tid >> 6, l = tid & 63;
    const int lrow = l & 15, lgrp = l >> 4, lk = lgrp * 8;
    const int h = w;                            // phase-1: wave = head
    const int mhat = w & 1, chat = w >> 1;      // phase-2: 2m-subtile x 4c

    const unsigned short* Wpb = Wp + ((size_t)b * NP_) * C_;
    const unsigned short* Ub  = U  + ((size_t)b * C_) * NP_;

    // Wp K=64 slice s -> [n 640][128B]; src chunk (q^(n&7)); 10 instr/wave
    auto stage_wp = [&](int s) {
        #pragma unroll
        for (int j = 0; j < 10; ++j) {
            int ch = w * 640 + j * 64 + l;      // 0..5119
            int n = ch >> 3, q = ch & 7;
            gld16(Wpb + (size_t)n * C_ + s * 64 + ((q ^ (n & 7)) << 3),
                  WB + ch * 16);
        }
    };
    // U n-slice nt (n in [nt*64, nt*64+64)) -> [c 320][128B]; 5 instr/wave
    auto stage_u = [&](int nt, char* buf) {
        #pragma unroll
        for (int j = 0; j < 5; ++j) {
            int ch = w * 320 + j * 64 + l;      // 0..2559
            int c = ch >> 3, q = ch & 7;
            gld16(Ub + (size_t)c * NP_ + nt * 64 + ((q ^ (c & 7)) << 3),
                  buf + ch * 16);
        }
    };

    // ---- prologue: hs 128x320 f32 -> bf16 into HS (swizzled)
    const float4* hv = (const float4*)(hs + ((size_t)b * S_ + s0) * C_);
    #pragma unroll
    for (int it = 0; it < 20; ++it) {           // 20*512 = 10240 float4
        int i = tid + it * 512;
        float4 v = hv[i];
        int r = i / 80, c = (i * 4) % C_;
        ushort4 u;
        u.x = f2bf(v.x); u.y = f2bf(v.y); u.z = f2bf(v.z); u.w = f2bf(v.w);
        int a = (r * 640 + c * 2) ^ ((r & 7) << 4);
        *(ushort4*)(HS + a) = u;
    }
    __syncthreads();        // drains hv vmem + hs ds_writes; HS visible
    stage_wp(0);

    // ---- phase 1: D[kk][m] for both subtiles, 5 K=64 slices
    f32x4 accA[5][4], accB[5][4];
    #pragma unroll
    for (int nf = 0; nf < 5; ++nf)
        #pragma unroll
        for (int mf = 0; mf < 4; ++mf) {
            accA[nf][mf] = (f32x4){0.f, 0.f, 0.f, 0.f};
            accB[nf][mf] = (f32x4){0.f, 0.f, 0.f, 0.f};
        }
    #pragma unroll
    for (int s = 0; s < 5; ++s) {
        WAITV(0);                               // own chunks of slice s done
        BAR();                                  // slice s fully landed
        #pragma unroll
        for (int ss = 0; ss < 2; ++ss) {
            bf16x8 bC[5], hfA[4], hfB[4];
            #pragma unroll
            for (int nf = 0; nf < 5; ++nf) {
                int n = h * KP_ + nf * 16 + lrow;
                bC[nf] = *(const bf16x8*)(WB + n * 128 +
                    ((ss * 64 + lgrp * 16) ^ ((n & 7) << 4)));
            }
            #pragma unroll
            for (int mf = 0; mf < 4; ++mf) {
                int ks32 = 2 * s + ss;
                int rowA = mf * 16 + lrow;
                hfA[mf] = *(const bf16x8*)(HS +
                    ((rowA * 640 + (ks32 * 32 + lk) * 2) ^ ((rowA & 7) << 4)));
                int rowB = 64 + mf * 16 + lrow;
                hfB[mf] = *(const bf16x8*)(HS +
                    ((rowB * 640 + (ks32 * 32 + lk) * 2) ^ ((rowB & 7) << 4)));
            }
            WAITLG();                           // reads in regs
            if (ss == 1) {
                BAR();                          // all waves done reading WB
                if (s < 4) stage_wp(s + 1);     // refill; lands under MFMA
            }
            __builtin_amdgcn_s_setprio(1);
            #pragma unroll
            for (int nf = 0; nf < 5; ++nf)
                #pragma unroll
                for (int mf = 0; mf < 4; ++mf) {
                    accA[nf][mf] = __builtin_amdgcn_mfma_f32_16x16x32_bf16(
                        bC[nf], hfA[mf], accA[nf][mf], 0, 0, 0);
                    accB[nf][mf] = __builtin_amdgcn_mfma_f32_16x16x32_bf16(
                        bC[nf], hfB[mf], accB[nf][mf], 0, 0, 0);
                }
            __builtin_amdgcn_s_setprio(0);
        }
    }

    // ---- penalty (loaded late to keep phase-1 regs/vmcnt clean)
    float4 pv4[5];
    #pragma unroll
    for (int nf = 0; nf < 5; ++nf)
        pv4[nf] = *(const float4*)(pen + b * KP_ + nf * 16 + lgrp * 4);
    WAITV(0);

    // ---- softmax (both subtiles) + pack P to bf16 in regs
    ushort4 pk[2][4][5];                        // [subtile][mf][nf], 80 VGPR
    #pragma unroll
    for (int X = 0; X < 2; ++X) {
        #pragma unroll
        for (int mf = 0; mf < 4; ++mf) {
            f32x4* acc = X ? &accB[0][mf] : &accA[0][mf];   // stride 4 in nf
            float mx = -1e30f;
            #pragma unroll
            for (int nf = 0; nf < 5; ++nf)
                #pragma unroll
                for (int r = 0; r < 4; ++r) {
                    float x = (X ? accB[nf][mf][r] : accA[nf][mf][r])
                              - ((const float*)&pv4[nf])[r];
                    if (nf == 4 && r >= 1) x = (lgrp == 3) ? -1e30f : x;
                    if (X) accB[nf][mf][r] = x; else accA[nf][mf][r] = x;
                    mx = fmaxf(mx, x);
                }
            mx = fmaxf(mx, __shfl_xor(mx, 16));
            mx = fmaxf(mx, __shfl_xor(mx, 32));
            float sum = 0.f;
            #pragma unroll
            for (int nf = 0; nf < 5; ++nf)
                #pragma unroll
                for (int r = 0; r < 4; ++r) {
                    float e = __expf((X ? accB[nf][mf][r] : accA[nf][mf][r]) - mx);
                    if (X) accB[nf][mf][r] = e; else accA[nf][mf][r] = e;
                    sum += e;
                }
            sum += __shfl_xor(sum, 16);
            sum += __shfl_xor(sum, 32);
            float inv = 1.f / sum;
            #pragma unroll
            for (int nf = 0; nf < 5; ++nf) {
                ushort4 u;
                u.x = f2bf((X ? accB[nf][mf][0] : accA[nf][mf][0]) * inv);
                u.y = f2bf((X ? accB[nf][mf][1] : accA[nf][mf][1]) * inv);
                u.z = f2bf((X ? accB[nf][mf][2] : accA[nf][mf][2]) * inv);
                u.w = f2bf((X ? accB[nf][mf][3] : accA[nf][mf][3]) * inv);
                pk[X][mf][nf] = u;
            }
        }
    }

    // heads 0..3: write P half-A now (PB overlays HS; phase-1 reads done via
    // the s=4/ss=1 BAR)
    if (h < 4) {
        #pragma unroll
        for (int X = 0; X < 2; ++X)
            #pragma unroll
            for (int mf = 0; mf < 4; ++mf) {
                int row = X * 64 + mf * 16 + lrow;
                #pragma unroll
                for (int nf = 0; nf < 5; ++nf) {
                    int col = (h & 3) * KP_ + nf * 16 + lgrp * 4;
                    *(ushort4*)(PB + ((row * 640 + col * 2) ^ ((row & 7) << 4)))
                        = pk[X][mf][nf];
                }
            }
    }

    // ---- phase 2: two n-half passes, U staged once, acc2 spans passes
    f32x4 acc2[5][4];                           // [nf: c-group][mf: m-group]
    #pragma unroll
    for (int nf = 0; nf < 5; ++nf)
        #pragma unroll
        for (int mf = 0; mf < 4; ++mf) acc2[nf][mf] = (f32x4){0.f, 0.f, 0.f, 0.f};
    #pragma unroll
    for (int p = 0; p < 2; ++p) {
        stage_u(p * 5 + 0, U0);
        stage_u(p * 5 + 1, U1);
        WAITVL(5);                              // slice p*5 landed + ds done
        BAR();                                  // P-half + U slice visible
        #pragma unroll
        for (int t = 0; t < 5; ++t) {
            char* ub = (t & 1) ? U1 : U0;
            #pragma unroll
            for (int ss = 0; ss < 2; ++ss) {
                bf16x8 pa[4], uf[5];
                #pragma unroll
                for (int mf = 0; mf < 4; ++mf) {
                    int row = mhat * 64 + mf * 16 + lrow;
                    pa[mf] = *(const bf16x8*)(PB + ((row * 640 +
                        t * 128 + ss * 64 + lgrp * 16) ^ ((row & 7) << 4)));
                }
                #pragma unroll
                for (int nf = 0; nf < 5; ++nf) {
                    int c = chat * KP_ + nf * 16 + lrow;
                    uf[nf] = *(const bf16x8*)(ub + c * 128 +
                        ((ss * 64 + lgrp * 16) ^ ((c & 7) << 4)));
                }
                WAITLG();                       // reads in regs
                if (ss == 1) {
                    BAR();                      // all waves done reading ub
                    if (t < 3) stage_u(p * 5 + t + 2, ub);
                }
                __builtin_amdgcn_s_setprio(1);
                #pragma unroll
                for (int nf = 0; nf < 5; ++nf)
                    #pragma unroll
                    for (int mf = 0; mf < 4; ++mf)
                        acc2[nf][mf] = __builtin_amdgcn_mfma_f32_16x16x32_bf16(
                            pa[mf], uf[nf], acc2[nf][mf], 0, 0, 0);
                __builtin_amdgcn_s_setprio(0);
            }
            if (t < 3)      { WAITV(5); BAR(); }   // slice t+1 landed
            else if (t == 3){ WAITV(0); BAR(); }
            // t==4: ss==1 BAR was the pass-final read-barrier
        }
        if (p == 0 && h >= 4) {
            // write P half-B (PB reads of pass 0 done via t=4/ss=1 BAR)
            #pragma unroll
            for (int X = 0; X < 2; ++X)
                #pragma unroll
                for (int mf = 0; mf < 4; ++mf) {
                    int row = X * 64 + mf * 16 + lrow;
                    #pragma unroll
                    for (int nf = 0; nf < 5; ++nf) {
                        int col = (h & 3) * KP_ + nf * 16 + lgrp * 4;
                        *(ushort4*)(PB + ((row * 640 + col * 2) ^ ((row & 7) << 4)))
                            = pk[X][mf][nf];
                    }
                }
        }
    }

    // ---- epilogue
    float bov[5];
    #pragma unroll
    for (int nf = 0; nf < 5; ++nf) bov[nf] = bo[chat * KP_ + nf * 16 + lrow];
    float* op = out + ((size_t)b * S_ + s0 + mhat * 64) * C_;
    #pragma unroll
    for (int mf = 0; mf < 4; ++mf)
        #pragma unroll
        for (int r = 0; r < 4; ++r)
            #pragma unroll
            for (int nf = 0; nf < 5; ++nf)
                op[(size_t)(mf * 16 + lgrp * 4 + r) * C_ +
                   chat * KP_ + nf * 16 + lrow] = acc2[nf][mf][r] + bov[nf];
}

// ---------------------------------------------------------------- launch
extern "C" void kernel_launch(void* const* d_in, const int* in_sizes, int n_in,
                              void* d_out, int out_size, void* d_ws, size_t ws_size,
                              hipStream_t stream) {
    const float* hs   = (const float*)d_in[0];
    const float* ehs  = (const float*)d_in[1];
    const float* harm = (const float*)d_in[2];
    const float* Wq   = (const float*)d_in[3];
    const float* Wk   = (const float*)d_in[4];
    const float* Wv   = (const float*)d_in[5];
    const float* Wo   = (const float*)d_in[6];
    const float* bo   = (const float*)d_in[7];
    float* out = (float*)d_out;

    char* ws = (char*)d_ws;
    unsigned short* ehs_bf = (unsigned short*)(ws);             //  1,966,080
    unsigned short* Bmat   = (unsigned short*)(ws + 1966080);   //  7,864,320
    float*          pen    = (float*)        (ws + 9830400);    //      5,120
    unsigned short* Wp     = (unsigned short*)(ws + 9835520);   //  6,553,600
    unsigned short* U      = (unsigned short*)(ws + 16389120);  //  6,553,600

    build_M <<<dim3(3, 8, 8),  256, 0, stream>>>(Wq, Wk, Wv, Wo, Bmat);
    prep_ehs<<<dim3(20, 16),   256, 0, stream>>>(ehs, harm, ehs_bf, pen);
    gemm_WpU<<<dim3(160),     1024, 0, stream>>>(ehs_bf, Bmat, Wp, U);
    fused_attn<<<dim3(512),    512, 0, stream>>>(hs, Wp, U, pen, bo, out);
}